// Round 1
// 2097.679 us; speedup vs baseline: 1.0262x; 1.0262x over previous
//
#include <hip/hip_runtime.h>
#include <cstdint>
#include <cstddef>

typedef _Float16 h2_t __attribute__((ext_vector_type(2)));
typedef unsigned int uint;
typedef unsigned short ushortt;

#define BB 128
#define TT 512

// ---- ws layout (bytes) ----
#define OFF_PRF0 0u           // 15*1024*16 = 245760  (RF image, layer0)
#define OFF_PLD0 245760u      // 9*1024*16  = 147456  (LDS image)
#define OFF_PRF1 393216u      // 245760
#define OFF_PLD1 638976u      // 147456
#define OFF_PI0  786432u      // 98304
#define OFF_PI1  884736u      // 393216
#define OFF_H2O  1277952u     // 131072
#define OFF_H1   1409024u     // 33554432
#define OFF_GX   34963456u    // 100663296 (end ~135.6 MB)

__device__ __forceinline__ uint pack2(float a, float b){
  h2_t h; h.x = (_Float16)a; h.y = (_Float16)b;
  return __builtin_bit_cast(uint, h);
}
__device__ __forceinline__ float f16f(ushortt s){
  return (float)__builtin_bit_cast(_Float16, s);
}
__device__ __forceinline__ ushortt ff16(float f){
  return __builtin_bit_cast(ushortt, (_Float16)f);
}
__device__ __forceinline__ float dot2(uint w, uint h, float acc){
  return __builtin_amdgcn_fdot2(__builtin_bit_cast(h2_t, w),
                                __builtin_bit_cast(h2_t, h), acc, false);
}
__device__ __forceinline__ float d16(uint4 w, uint4 h, float a){
  a = dot2(w.x,h.x,a); a = dot2(w.y,h.y,a);
  a = dot2(w.z,h.z,a); a = dot2(w.w,h.w,a);
  return a;
}
template<int CTRL>
__device__ __forceinline__ float dpp_addf(float x){
  int p = __builtin_amdgcn_update_dpp(0, __float_as_int(x), CTRL, 0xF, 0xF, true);
  return x + __int_as_float(p);
}
template<int CTRL>
__device__ __forceinline__ float dpp_movf(float x){
  return __int_as_float(__builtin_amdgcn_update_dpp(0, __float_as_int(x), CTRL, 0xF, 0xF, true));
}
// sum over 4-lane quads, result in all 4 lanes (verified r4-r8)
__device__ __forceinline__ float red4(float x){
  x = dpp_addf<0xB1>(x); x = dpp_addf<0x4E>(x);
  return x;
}
// sum over 8-lane groups (q = lane&7), result in all 8 lanes (verified r1..r7)
__device__ __forceinline__ float red8(float x){
  x = dpp_addf<0xB1>(x); x = dpp_addf<0x4E>(x);
  int y = __builtin_amdgcn_ds_swizzle(__float_as_int(x), 0x101F);
  return x + __int_as_float(y);
}
__device__ __forceinline__ float sigf(float x){ return 1.0f/(1.0f+__expf(-x)); }
__device__ __forceinline__ float tanhf_(float x){
  x = fminf(15.0f, fmaxf(-15.0f, x));
  float e = __expf(2.0f*x);
  return (e-1.0f)/(e+1.0f);
}

// =================== prep: pack fp32 weights -> f16 images ===================
// REC org (r5/r7-verified): thread (q=tid&7, u=tid>>3, units 2u,2u+1);
// chunk c = r*4+k4, r = g*2+s: row = g*256+2u+s, dword e = cols 32q+8k4+2e,+1.
// r10 split: c<15 -> PRF (register-resident, 60 VGPRs pinned), else -> PLD (LDS).
// No streamed tier anymore.
__global__ void prep_kernel(const float* __restrict__ W_ih0, const float* __restrict__ W_hh0,
                            const float* __restrict__ W_ih1, const float* __restrict__ W_hh1,
                            uint* __restrict__ PRF0, uint* __restrict__ PLD0,
                            uint* __restrict__ PRF1, uint* __restrict__ PLD1,
                            uint* __restrict__ PI0, uint* __restrict__ PI1)
{
  int i = blockIdx.x*256 + threadIdx.x;
  if (i < 196608) {
    const int layer = (i >= 98304) ? 1 : 0;
    const float* W = layer ? W_hh1 : W_hh0;
    int j = layer ? (i - 98304) : i;
    int e = j&3, r2 = j>>2;
    int tid = r2 & 1023, c = r2 >> 10;
    int q = tid&7, u = tid>>3, k4 = c&3, r = c>>2;
    int g = r>>1, s = r&1;
    int row = g*256 + 2*u + s, col = 32*q + 8*k4 + 2*e;
    uint val = pack2(W[row*256+col], W[row*256+col+1]);
    if (c < 15) (layer ? PRF1 : PRF0)[j]         = val;
    else        (layer ? PLD1 : PLD0)[j - 61440] = val;
  } else if (i < 221184) {
    int j2 = i - 196608;
    int jj = j2 & 255, rc = j2 >> 8;
    int ci = rc & 31, r = rc >> 5;
    PI0[j2] = pack2(W_ih0[(r*256+jj)*64 + 2*ci], W_ih0[(r*256+jj)*64 + 2*ci + 1]);
  } else if (i < 319488) {
    int j3 = i - 221184;
    int tid = j3 & 1023, rc = j3 >> 10;
    int ci = rc & 31, r = rc >> 5;
    int kq = tid & 3, jj = tid >> 2;
    int col = 64*kq + 2*ci;
    PI1[j3] = pack2(W_ih1[(r*256+jj)*256 + col], W_ih1[(r*256+jj)*256 + col + 1]);
  }
}

// =================== GEMM0: gx0 = W_ih0 . x + biases (unchanged from r5) ===================
__global__ __launch_bounds__(512) void gemm0_kernel(
    const float* __restrict__ x, const uint* __restrict__ PI0,
    const float* __restrict__ b_ih0, const float* __restrict__ b_hh0,
    ushortt* __restrict__ gx)
{
  const int blk = blockIdx.x;
  const int b = blk >> 4, t0 = (blk & 15) * 32;
  const int tid = threadIdx.x;
  const int j = tid & 255, th = tid >> 8;
  __shared__ uint xs[32*32];
  {
    float4 v = ((const float4*)x)[((size_t)b*TT + t0 + (tid>>4))*16 + (tid&15)];
    xs[(tid>>4)*32 + (tid&15)*2]     = pack2(v.x, v.y);
    xs[(tid>>4)*32 + (tid&15)*2 + 1] = pack2(v.z, v.w);
  }
  uint w[96];
  #pragma unroll
  for (int rc = 0; rc < 96; ++rc) w[rc] = PI0[rc*256 + j];
  const float br = b_ih0[j] + b_hh0[j];
  const float bz = b_ih0[256+j] + b_hh0[256+j];
  const float bn = b_ih0[512+j];
  __syncthreads();
  ushortt* gout = gx + ((size_t)b*TT + t0 + th*16)*768;
  #pragma unroll 1
  for (int tt = 0; tt < 16; ++tt) {
    const uint* xr = xs + (th*16 + tt)*32;
    float ar=0.f, az=0.f, an=0.f;
    #pragma unroll
    for (int c = 0; c < 32; ++c) {
      uint xv = xr[c];
      ar = dot2(w[c],    xv, ar);
      az = dot2(w[32+c], xv, az);
      an = dot2(w[64+c], xv, an);
    }
    gout[j]     = ff16(ar + br);
    gout[256+j] = ff16(az + bz);
    gout[512+j] = ff16(an + bn);
    gout += 768;
  }
}

// =================== GEMM1: gx1 = W_ih1 . h1 + biases (unchanged from r5) ===================
__global__ __launch_bounds__(1024) void gemm1_kernel(
    const uint* __restrict__ h1, const uint* __restrict__ PI1,
    const float* __restrict__ b_ih1, const float* __restrict__ b_hh1,
    ushortt* __restrict__ gx)
{
  const int blk = blockIdx.x;
  const int b = blk >> 5, t0 = (blk & 31) * 16;
  const int tid = threadIdx.x;
  const int kq = tid & 3, j = tid >> 2;
  __shared__ uint hsT[16*144];
  {
    uint2 v = ((const uint2*)(h1 + ((size_t)b*TT + t0)*128))[tid];
    int f = 2*tid, tp = f>>7, c = f&127, s = c>>2, e = c&3;
    *(uint2*)&hsT[tp*144 + (s + (s>>3))*4 + e] = v;
  }
  uint w[96];
  #pragma unroll
  for (int rc = 0; rc < 96; ++rc) w[rc] = PI1[rc*1024 + tid];
  const float br = b_ih1[j] + b_hh1[j];
  const float bz = b_ih1[256+j] + b_hh1[256+j];
  const float bn = b_ih1[512+j];
  __syncthreads();
  ushortt* gout = gx + ((size_t)b*TT + t0)*768;
  #pragma unroll 1
  for (int tt = 0; tt < 16; ++tt) {
    const uint4* hr = (const uint4*)&hsT[tt*144];
    float ar=0.f, az=0.f, an=0.f;
    #pragma unroll
    for (int i = 0; i < 8; ++i) {
      uint4 hv = hr[9*kq + i];
      ar = dot2(w[4*i],hv.x,ar);    ar = dot2(w[4*i+1],hv.y,ar);
      ar = dot2(w[4*i+2],hv.z,ar);  ar = dot2(w[4*i+3],hv.w,ar);
      az = dot2(w[32+4*i],hv.x,az); az = dot2(w[32+4*i+1],hv.y,az);
      az = dot2(w[32+4*i+2],hv.z,az); az = dot2(w[32+4*i+3],hv.w,az);
      an = dot2(w[64+4*i],hv.x,an); an = dot2(w[64+4*i+1],hv.y,an);
      an = dot2(w[64+4*i+2],hv.z,an); an = dot2(w[64+4*i+3],hv.w,an);
    }
    ar = red4(ar); az = red4(az); an = red4(an);
    if (kq == 0) {
      gout[j]     = ff16(ar + br);
      gout[256+j] = ff16(az + bz);
      gout[512+j] = ff16(an + bn);
    }
    gout += 768;
  }
}

// =================== REC: serial GRU recurrence (r10: no L2 stream, raw barrier) ===================
// r9 structure with the streamed tier eliminated:
//   c=0..14  -> RF, pinned scalars (60 VGPRs; 16 waves/CU allows 128 VGPR/thread)
//   c=15..23 -> LDS, per-thread-private, stride-9 quads (147 KB)
// Accumulation order per accumulator stays ascending-c (RF chain then LDS chain)
// -> bit-identical rounding vs r9.
// Per-step barrier is raw `s_waitcnt lgkmcnt(0); s_barrier` (single asm, memory
// clobber): only LDS h-dbuf ordering is required; the global gx 2-ahead prefetch
// stays in flight across the barrier instead of being drained by __syncthreads'
// vmcnt(0), realizing ~1 full step of load slack.
template<bool IS_L0>
__global__ __launch_bounds__(1024) void rec_kernel(
    const uint4* __restrict__ PRF, const uint4* __restrict__ PLD,
    const ushortt* __restrict__ GX, const float* __restrict__ b_hh,
    uint* __restrict__ h1, float* __restrict__ h2o)
{
  extern __shared__ uint lds_u[];           // [0,36864): ldsw quads; [36864,37184): h dbuf
  uint4* ldsw  = (uint4*)lds_u;             // [1024][9] per-thread-private (c=15..23)
  uint*  hbase = lds_u + 36864;             // 2 x 160 uints (padded phys = c + 4*(c>>4))
  const int b = blockIdx.x, tid = threadIdx.x;
  const int q = tid & 7, u = tid >> 3;

  #pragma unroll
  for (int i = 0; i < 9; ++i) ldsw[tid*9 + i] = PLD[i*1024 + tid];
  if (tid < 320) hbase[tid] = 0;

  uint w[60];
  #pragma unroll
  for (int c = 0; c < 15; ++c) {
    uint4 v = PRF[c*1024 + tid];
    w[4*c] = v.x; w[4*c+1] = v.y; w[4*c+2] = v.z; w[4*c+3] = v.w;
  }
  #pragma unroll
  for (int c = 0; c < 60; ++c) asm volatile("" : "+v"(w[c]));  // r7-verified pin idiom

  const int j = 2*u + q;                // unit index (valid for q<2)
  const bool gl = (q < 2);
  const ushortt* gxp = GX + (size_t)b*TT*768;
  const float bhn = gl ? b_hh[512 + j] : 0.f;
  ushortt gr0=0, gz0=0, gn0=0, gr1=0, gz1=0, gn1=0;
  if (gl) {
    gr0 = gxp[j]; gz0 = gxp[256+j]; gn0 = gxp[512+j];
    gr1 = gxp[768+j]; gz1 = gxp[768+256+j]; gn1 = gxp[768+512+j];
  }
  float h_old = 0.f;
  __syncthreads();
  int cur = 0;
  #pragma unroll 1
  for (int t = 0; t < TT; ++t) {
    const uint4* hr = (const uint4*)&hbase[cur*160];
    uint4 hk[4];
    #pragma unroll
    for (int k4 = 0; k4 < 4; ++k4) hk[k4] = hr[5*q + k4];  // phys 20q+4k4, conflict-free (r7)

    float a[6] = {0.f,0.f,0.f,0.f,0.f,0.f};   // a[r], r=g*2+s: r/z/n gates x units 2u,2u+1
    // RF: c = 0..14
    #pragma unroll
    for (int c = 0; c < 15; ++c) {
      uint4 wv; wv.x = w[4*c]; wv.y = w[4*c+1]; wv.z = w[4*c+2]; wv.w = w[4*c+3];
      a[c>>2] = d16(wv, hk[c&3], a[c>>2]);
    }
    // LDS: c = 15..23
    #pragma unroll
    for (int i = 0; i < 9; ++i) {
      const int c = 15 + i;
      a[c>>2] = d16(ldsw[tid*9 + i], hk[c&3], a[c>>2]);
    }
    #pragma unroll
    for (int r6 = 0; r6 < 6; ++r6) a[r6] = red8(a[r6]);

    const bool odd = (q & 1);
    float Sr = odd ? a[1] : a[0];
    float Sz = odd ? a[3] : a[2];
    float Sn = odd ? a[5] : a[4];
    float r = sigf(f16f(gr0) + Sr);
    float z = sigf(f16f(gz0) + Sz);
    float n = tanhf_(f16f(gn0) + r*(Sn + bhn));
    float hn = z*(h_old - n) + n;
    if (gl) h_old = hn;
    gr0 = gr1; gz0 = gz1; gn0 = gn1;
    if (gl && t + 2 < TT) {
      const ushortt* p = gxp + (size_t)(t+2)*768;
      gr1 = p[j]; gz1 = p[256+j]; gn1 = p[512+j];
    }
    float hx = dpp_movf<0xB1>(hn);
    uint hv2 = pack2(hn, hx);
    if (q == 0) {
      hbase[(cur^1)*160 + u + 4*(u>>4)] = hv2;
      if (IS_L0) h1[((size_t)b*TT + t)*128 + u] = hv2;
    }
    if (!IS_L0 && t == TT-1 && gl) h2o[b*256 + j] = hn;
    // LDS-only barrier: drain ds ops, leave global prefetch (vmcnt) in flight.
    asm volatile("s_waitcnt lgkmcnt(0)\n\ts_barrier" ::: "memory");
    cur ^= 1;
  }
}

// =================== MLP head (unchanged) ===================
__global__ __launch_bounds__(128) void mlp_kernel(
    const float* __restrict__ h2, const float* __restrict__ W1,
    const float* __restrict__ b1, const float* __restrict__ W2,
    const float* __restrict__ b2, float* __restrict__ out)
{
  __shared__ float hls[256];
  __shared__ float red[128];
  const int b = blockIdx.x, tid = threadIdx.x;
  if (tid < 64) ((float4*)hls)[tid] = ((const float4*)(h2 + (size_t)b*256))[tid];
  __syncthreads();
  float acc = b1[tid];
  const float4* w4 = (const float4*)(W1 + (size_t)tid*256);
  const float4* h4 = (const float4*)hls;
  #pragma unroll 8
  for (int k = 0; k < 64; ++k) {
    float4 w = w4[k]; float4 h = h4[k];
    acc = fmaf(w.x,h.x,acc); acc = fmaf(w.y,h.y,acc);
    acc = fmaf(w.z,h.z,acc); acc = fmaf(w.w,h.w,acc);
  }
  red[tid] = fmaxf(acc, 0.0f) * W2[tid];
  __syncthreads();
  for (int s = 64; s > 0; s >>= 1) {
    if (tid < s) red[tid] += red[tid + s];
    __syncthreads();
  }
  if (tid == 0) out[b] = red[0] + b2[0];
}

extern "C" void kernel_launch(void* const* d_in, const int* in_sizes, int n_in,
                              void* d_out, int out_size, void* d_ws, size_t ws_size,
                              hipStream_t stream)
{
  const float* x     = (const float*)d_in[0];
  const float* W_ih0 = (const float*)d_in[1];
  const float* W_hh0 = (const float*)d_in[2];
  const float* b_ih0 = (const float*)d_in[3];
  const float* b_hh0 = (const float*)d_in[4];
  const float* W_ih1 = (const float*)d_in[5];
  const float* W_hh1 = (const float*)d_in[6];
  const float* b_ih1 = (const float*)d_in[7];
  const float* b_hh1 = (const float*)d_in[8];
  const float* W1    = (const float*)d_in[9];
  const float* b1    = (const float*)d_in[10];
  const float* W2    = (const float*)d_in[11];
  const float* b2    = (const float*)d_in[12];

  char* ws = (char*)d_ws;
  uint*    PRF0 = (uint*)(ws + OFF_PRF0);
  uint*    PLD0 = (uint*)(ws + OFF_PLD0);
  uint*    PRF1 = (uint*)(ws + OFF_PRF1);
  uint*    PLD1 = (uint*)(ws + OFF_PLD1);
  uint*    PI0  = (uint*)(ws + OFF_PI0);
  uint*    PI1  = (uint*)(ws + OFF_PI1);
  float*   H2O  = (float*)(ws + OFF_H2O);
  uint*    H1   = (uint*)(ws + OFF_H1);
  ushortt* GX   = (ushortt*)(ws + OFF_GX);

  const int rec_lds = 36864*4 + 320*4;   // 148736 B
  (void)hipFuncSetAttribute(reinterpret_cast<const void*>(&rec_kernel<true>),
                            hipFuncAttributeMaxDynamicSharedMemorySize, rec_lds);
  (void)hipFuncSetAttribute(reinterpret_cast<const void*>(&rec_kernel<false>),
                            hipFuncAttributeMaxDynamicSharedMemorySize, rec_lds);

  prep_kernel<<<1248, 256, 0, stream>>>(W_ih0, W_hh0, W_ih1, W_hh1,
                                        PRF0, PLD0, PRF1, PLD1, PI0, PI1);
  gemm0_kernel<<<2048, 512, 0, stream>>>(x, PI0, b_ih0, b_hh0, GX);
  rec_kernel<true><<<BB, 1024, rec_lds, stream>>>((const uint4*)PRF0, (const uint4*)PLD0,
                                                  GX, b_hh0, H1, nullptr);
  gemm1_kernel<<<4096, 1024, 0, stream>>>(H1, PI1, b_ih1, b_hh1, GX);
  rec_kernel<false><<<BB, 1024, rec_lds, stream>>>((const uint4*)PRF1, (const uint4*)PLD1,
                                                   GX, b_hh1, nullptr, H2O);
  mlp_kernel<<<BB, 128, 0, stream>>>(H2O, W1, b1, W2, b2, (float*)d_out);
}

// Round 2
// 2085.065 us; speedup vs baseline: 1.0324x; 1.0060x over previous
//
#include <hip/hip_runtime.h>
#include <cstdint>
#include <cstddef>

typedef _Float16 h2_t __attribute__((ext_vector_type(2)));
typedef unsigned int uint;
typedef unsigned short ushortt;

#define BB 128
#define TT 512

// ---- ws layout (bytes) ----
#define OFF_PRF0 0u           // 15*1024*16 = 245760  (RF image, layer0)
#define OFF_PLD0 245760u      // 9*1024*16  = 147456  (LDS image)
#define OFF_PRF1 393216u      // 245760
#define OFF_PLD1 638976u      // 147456
#define OFF_PI0  786432u      // 98304
#define OFF_PI1  884736u      // 393216
#define OFF_H2O  1277952u     // 131072
#define OFF_H1   1409024u     // 33554432
#define OFF_GX   34963456u    // 100663296 (end ~135.6 MB)

__device__ __forceinline__ uint pack2(float a, float b){
  h2_t h; h.x = (_Float16)a; h.y = (_Float16)b;
  return __builtin_bit_cast(uint, h);
}
__device__ __forceinline__ float f16f(ushortt s){
  return (float)__builtin_bit_cast(_Float16, s);
}
__device__ __forceinline__ ushortt ff16(float f){
  return __builtin_bit_cast(ushortt, (_Float16)f);
}
__device__ __forceinline__ float dot2(uint w, uint h, float acc){
  return __builtin_amdgcn_fdot2(__builtin_bit_cast(h2_t, w),
                                __builtin_bit_cast(h2_t, h), acc, false);
}
__device__ __forceinline__ float d16(uint4 w, uint4 h, float a){
  a = dot2(w.x,h.x,a); a = dot2(w.y,h.y,a);
  a = dot2(w.z,h.z,a); a = dot2(w.w,h.w,a);
  return a;
}
template<int CTRL>
__device__ __forceinline__ float dpp_addf(float x){
  int p = __builtin_amdgcn_update_dpp(0, __float_as_int(x), CTRL, 0xF, 0xF, true);
  return x + __int_as_float(p);
}
template<int CTRL>
__device__ __forceinline__ float dpp_movf(float x){
  return __int_as_float(__builtin_amdgcn_update_dpp(0, __float_as_int(x), CTRL, 0xF, 0xF, true));
}
// sum over 4-lane quads, result in all 4 lanes (verified r4-r8)
__device__ __forceinline__ float red4(float x){
  x = dpp_addf<0xB1>(x); x = dpp_addf<0x4E>(x);
  return x;
}
// sum over 8-lane groups (q = lane&7), result in all 8 lanes (verified r1..r7)
__device__ __forceinline__ float red8(float x){
  x = dpp_addf<0xB1>(x); x = dpp_addf<0x4E>(x);
  int y = __builtin_amdgcn_ds_swizzle(__float_as_int(x), 0x101F);
  return x + __int_as_float(y);
}
__device__ __forceinline__ float sigf(float x){ return 1.0f/(1.0f+__expf(-x)); }
__device__ __forceinline__ float tanhf_(float x){
  x = fminf(15.0f, fmaxf(-15.0f, x));
  float e = __expf(2.0f*x);
  return (e-1.0f)/(e+1.0f);
}

// =================== prep: pack fp32 weights -> f16 images ===================
// REC org (r5/r7-verified): thread (q=tid&7, u=tid>>3, units 2u,2u+1);
// chunk c = r*4+k4, r = g*2+s: row = g*256+2u+s, dword e = cols 32q+8k4+2e,+1.
// r10/r11 split: c<15 -> PRF (register-resident), else -> PLD (LDS).
__global__ void prep_kernel(const float* __restrict__ W_ih0, const float* __restrict__ W_hh0,
                            const float* __restrict__ W_ih1, const float* __restrict__ W_hh1,
                            uint* __restrict__ PRF0, uint* __restrict__ PLD0,
                            uint* __restrict__ PRF1, uint* __restrict__ PLD1,
                            uint* __restrict__ PI0, uint* __restrict__ PI1)
{
  int i = blockIdx.x*256 + threadIdx.x;
  if (i < 196608) {
    const int layer = (i >= 98304) ? 1 : 0;
    const float* W = layer ? W_hh1 : W_hh0;
    int j = layer ? (i - 98304) : i;
    int e = j&3, r2 = j>>2;
    int tid = r2 & 1023, c = r2 >> 10;
    int q = tid&7, u = tid>>3, k4 = c&3, r = c>>2;
    int g = r>>1, s = r&1;
    int row = g*256 + 2*u + s, col = 32*q + 8*k4 + 2*e;
    uint val = pack2(W[row*256+col], W[row*256+col+1]);
    if (c < 15) (layer ? PRF1 : PRF0)[j]         = val;
    else        (layer ? PLD1 : PLD0)[j - 61440] = val;
  } else if (i < 221184) {
    int j2 = i - 196608;
    int jj = j2 & 255, rc = j2 >> 8;
    int ci = rc & 31, r = rc >> 5;
    PI0[j2] = pack2(W_ih0[(r*256+jj)*64 + 2*ci], W_ih0[(r*256+jj)*64 + 2*ci + 1]);
  } else if (i < 319488) {
    int j3 = i - 221184;
    int tid = j3 & 1023, rc = j3 >> 10;
    int ci = rc & 31, r = rc >> 5;
    int kq = tid & 3, jj = tid >> 2;
    int col = 64*kq + 2*ci;
    PI1[j3] = pack2(W_ih1[(r*256+jj)*256 + col], W_ih1[(r*256+jj)*256 + col + 1]);
  }
}

// =================== GEMM0: gx0 = W_ih0 . x + biases (unchanged from r5) ===================
__global__ __launch_bounds__(512) void gemm0_kernel(
    const float* __restrict__ x, const uint* __restrict__ PI0,
    const float* __restrict__ b_ih0, const float* __restrict__ b_hh0,
    ushortt* __restrict__ gx)
{
  const int blk = blockIdx.x;
  const int b = blk >> 4, t0 = (blk & 15) * 32;
  const int tid = threadIdx.x;
  const int j = tid & 255, th = tid >> 8;
  __shared__ uint xs[32*32];
  {
    float4 v = ((const float4*)x)[((size_t)b*TT + t0 + (tid>>4))*16 + (tid&15)];
    xs[(tid>>4)*32 + (tid&15)*2]     = pack2(v.x, v.y);
    xs[(tid>>4)*32 + (tid&15)*2 + 1] = pack2(v.z, v.w);
  }
  uint w[96];
  #pragma unroll
  for (int rc = 0; rc < 96; ++rc) w[rc] = PI0[rc*256 + j];
  const float br = b_ih0[j] + b_hh0[j];
  const float bz = b_ih0[256+j] + b_hh0[256+j];
  const float bn = b_ih0[512+j];
  __syncthreads();
  ushortt* gout = gx + ((size_t)b*TT + t0 + th*16)*768;
  #pragma unroll 1
  for (int tt = 0; tt < 16; ++tt) {
    const uint* xr = xs + (th*16 + tt)*32;
    float ar=0.f, az=0.f, an=0.f;
    #pragma unroll
    for (int c = 0; c < 32; ++c) {
      uint xv = xr[c];
      ar = dot2(w[c],    xv, ar);
      az = dot2(w[32+c], xv, az);
      an = dot2(w[64+c], xv, an);
    }
    gout[j]     = ff16(ar + br);
    gout[256+j] = ff16(az + bz);
    gout[512+j] = ff16(an + bn);
    gout += 768;
  }
}

// =================== GEMM1: gx1 = W_ih1 . h1 + biases (unchanged from r5) ===================
__global__ __launch_bounds__(1024) void gemm1_kernel(
    const uint* __restrict__ h1, const uint* __restrict__ PI1,
    const float* __restrict__ b_ih1, const float* __restrict__ b_hh1,
    ushortt* __restrict__ gx)
{
  const int blk = blockIdx.x;
  const int b = blk >> 5, t0 = (blk & 31) * 16;
  const int tid = threadIdx.x;
  const int kq = tid & 3, j = tid >> 2;
  __shared__ uint hsT[16*144];
  {
    uint2 v = ((const uint2*)(h1 + ((size_t)b*TT + t0)*128))[tid];
    int f = 2*tid, tp = f>>7, c = f&127, s = c>>2, e = c&3;
    *(uint2*)&hsT[tp*144 + (s + (s>>3))*4 + e] = v;
  }
  uint w[96];
  #pragma unroll
  for (int rc = 0; rc < 96; ++rc) w[rc] = PI1[rc*1024 + tid];
  const float br = b_ih1[j] + b_hh1[j];
  const float bz = b_ih1[256+j] + b_hh1[256+j];
  const float bn = b_ih1[512+j];
  __syncthreads();
  ushortt* gout = gx + ((size_t)b*TT + t0)*768;
  #pragma unroll 1
  for (int tt = 0; tt < 16; ++tt) {
    const uint4* hr = (const uint4*)&hsT[tt*144];
    float ar=0.f, az=0.f, an=0.f;
    #pragma unroll
    for (int i = 0; i < 8; ++i) {
      uint4 hv = hr[9*kq + i];
      ar = dot2(w[4*i],hv.x,ar);    ar = dot2(w[4*i+1],hv.y,ar);
      ar = dot2(w[4*i+2],hv.z,ar);  ar = dot2(w[4*i+3],hv.w,ar);
      az = dot2(w[32+4*i],hv.x,az); az = dot2(w[32+4*i+1],hv.y,az);
      az = dot2(w[32+4*i+2],hv.z,az); az = dot2(w[32+4*i+3],hv.w,az);
      an = dot2(w[64+4*i],hv.x,an); an = dot2(w[64+4*i+1],hv.y,an);
      an = dot2(w[64+4*i+2],hv.z,an); an = dot2(w[64+4*i+3],hv.w,an);
    }
    ar = red4(ar); az = red4(az); an = red4(an);
    if (kq == 0) {
      gout[j]     = ff16(ar + br);
      gout[256+j] = ff16(az + bz);
      gout[512+j] = ff16(an + bn);
    }
    gout += 768;
  }
}

// =================== REC: serial GRU recurrence (r11: force true RF residency) ===================
// r10's RF tier never materialized (VGPR_Count=60): the one-shot pin before the
// loop let LLVM rematerialize all 15 PRF quad-loads inside the loop -> 245 KB/CU/step
// of L2 traffic = the measured 4200 cy/step. r11:
//   (a) pin asm INSIDE the t-loop: the per-iteration "+v" asm is opaque, so the
//       weight values become un-rematerializable loop-carried registers.
//   (b) k4-outer / gate-inner chunk order with JIT hk load: one h-quad (4 VGPRs)
//       live at a time instead of 16, so the 60 live weights fit without spill.
//       Per-accumulator sum order unchanged (c=4r+k4 ascends in k4 for fixed r)
//       -> bit-identical numerics.
template<bool IS_L0>
__global__ __launch_bounds__(1024) void rec_kernel(
    const uint4* __restrict__ PRF, const uint4* __restrict__ PLD,
    const ushortt* __restrict__ GX, const float* __restrict__ b_hh,
    uint* __restrict__ h1, float* __restrict__ h2o)
{
  extern __shared__ uint lds_u[];           // [0,36864): ldsw quads; [36864,37184): h dbuf
  uint4* ldsw  = (uint4*)lds_u;             // [1024][9] per-thread-private (c=15..23)
  uint*  hbase = lds_u + 36864;             // 2 x 160 uints (padded phys = c + 4*(c>>4))
  const int b = blockIdx.x, tid = threadIdx.x;
  const int q = tid & 7, u = tid >> 3;

  #pragma unroll
  for (int i = 0; i < 9; ++i) ldsw[tid*9 + i] = PLD[i*1024 + tid];
  if (tid < 320) hbase[tid] = 0;

  uint w[60];
  #pragma unroll
  for (int c = 0; c < 15; ++c) {
    uint4 v = PRF[c*1024 + tid];
    w[4*c] = v.x; w[4*c+1] = v.y; w[4*c+2] = v.z; w[4*c+3] = v.w;
  }

  const int j = 2*u + q;                // unit index (valid for q<2)
  const bool gl = (q < 2);
  const ushortt* gxp = GX + (size_t)b*TT*768;
  const float bhn = gl ? b_hh[512 + j] : 0.f;
  ushortt gr0=0, gz0=0, gn0=0, gr1=0, gz1=0, gn1=0;
  if (gl) {
    gr0 = gxp[j]; gz0 = gxp[256+j]; gn0 = gxp[512+j];
    gr1 = gxp[768+j]; gz1 = gxp[768+256+j]; gn1 = gxp[768+512+j];
  }
  float h_old = 0.f;
  __syncthreads();
  int cur = 0;
  #pragma unroll 1
  for (int t = 0; t < TT; ++t) {
    // In-loop pin: each iteration's asm is opaque -> the 60 weight words are
    // loop-carried VGPRs that cannot be rematerialized from PRF.
    #pragma unroll
    for (int c = 0; c < 60; ++c) asm volatile("" : "+v"(w[c]));

    const uint4* hr = (const uint4*)&hbase[cur*160];
    float a[6] = {0.f,0.f,0.f,0.f,0.f,0.f};   // a[r], r=g*2+s: r/z/n gates x units 2u,2u+1
    // k4-outer, gate-inner: only one hk quad live at a time.
    #pragma unroll
    for (int k4 = 0; k4 < 4; ++k4) {
      uint4 hk = hr[5*q + k4];               // phys 20q+4k4, conflict-free (r7)
      #pragma unroll
      for (int r6 = 0; r6 < 6; ++r6) {
        const int c = r6*4 + k4;
        if (c < 15) {
          uint4 wv; wv.x = w[4*c]; wv.y = w[4*c+1]; wv.z = w[4*c+2]; wv.w = w[4*c+3];
          a[r6] = d16(wv, hk, a[r6]);
        } else {
          a[r6] = d16(ldsw[tid*9 + (c - 15)], hk, a[r6]);
        }
      }
    }
    #pragma unroll
    for (int r6 = 0; r6 < 6; ++r6) a[r6] = red8(a[r6]);

    const bool odd = (q & 1);
    float Sr = odd ? a[1] : a[0];
    float Sz = odd ? a[3] : a[2];
    float Sn = odd ? a[5] : a[4];
    float r = sigf(f16f(gr0) + Sr);
    float z = sigf(f16f(gz0) + Sz);
    float n = tanhf_(f16f(gn0) + r*(Sn + bhn));
    float hn = z*(h_old - n) + n;
    if (gl) h_old = hn;
    gr0 = gr1; gz0 = gz1; gn0 = gn1;
    if (gl && t + 2 < TT) {
      const ushortt* p = gxp + (size_t)(t+2)*768;
      gr1 = p[j]; gz1 = p[256+j]; gn1 = p[512+j];
    }
    float hx = dpp_movf<0xB1>(hn);
    uint hv2 = pack2(hn, hx);
    if (q == 0) {
      hbase[(cur^1)*160 + u + 4*(u>>4)] = hv2;
      if (IS_L0) h1[((size_t)b*TT + t)*128 + u] = hv2;
    }
    if (!IS_L0 && t == TT-1 && gl) h2o[b*256 + j] = hn;
    // LDS-only barrier: drain ds ops, leave global prefetch (vmcnt) in flight.
    asm volatile("s_waitcnt lgkmcnt(0)\n\ts_barrier" ::: "memory");
    cur ^= 1;
  }
}

// =================== MLP head (unchanged) ===================
__global__ __launch_bounds__(128) void mlp_kernel(
    const float* __restrict__ h2, const float* __restrict__ W1,
    const float* __restrict__ b1, const float* __restrict__ W2,
    const float* __restrict__ b2, float* __restrict__ out)
{
  __shared__ float hls[256];
  __shared__ float red[128];
  const int b = blockIdx.x, tid = threadIdx.x;
  if (tid < 64) ((float4*)hls)[tid] = ((const float4*)(h2 + (size_t)b*256))[tid];
  __syncthreads();
  float acc = b1[tid];
  const float4* w4 = (const float4*)(W1 + (size_t)tid*256);
  const float4* h4 = (const float4*)hls;
  #pragma unroll 8
  for (int k = 0; k < 64; ++k) {
    float4 w = w4[k]; float4 h = h4[k];
    acc = fmaf(w.x,h.x,acc); acc = fmaf(w.y,h.y,acc);
    acc = fmaf(w.z,h.z,acc); acc = fmaf(w.w,h.w,acc);
  }
  red[tid] = fmaxf(acc, 0.0f) * W2[tid];
  __syncthreads();
  for (int s = 64; s > 0; s >>= 1) {
    if (tid < s) red[tid] += red[tid + s];
    __syncthreads();
  }
  if (tid == 0) out[b] = red[0] + b2[0];
}

extern "C" void kernel_launch(void* const* d_in, const int* in_sizes, int n_in,
                              void* d_out, int out_size, void* d_ws, size_t ws_size,
                              hipStream_t stream)
{
  const float* x     = (const float*)d_in[0];
  const float* W_ih0 = (const float*)d_in[1];
  const float* W_hh0 = (const float*)d_in[2];
  const float* b_ih0 = (const float*)d_in[3];
  const float* b_hh0 = (const float*)d_in[4];
  const float* W_ih1 = (const float*)d_in[5];
  const float* W_hh1 = (const float*)d_in[6];
  const float* b_ih1 = (const float*)d_in[7];
  const float* b_hh1 = (const float*)d_in[8];
  const float* W1    = (const float*)d_in[9];
  const float* b1    = (const float*)d_in[10];
  const float* W2    = (const float*)d_in[11];
  const float* b2    = (const float*)d_in[12];

  char* ws = (char*)d_ws;
  uint*    PRF0 = (uint*)(ws + OFF_PRF0);
  uint*    PLD0 = (uint*)(ws + OFF_PLD0);
  uint*    PRF1 = (uint*)(ws + OFF_PRF1);
  uint*    PLD1 = (uint*)(ws + OFF_PLD1);
  uint*    PI0  = (uint*)(ws + OFF_PI0);
  uint*    PI1  = (uint*)(ws + OFF_PI1);
  float*   H2O  = (float*)(ws + OFF_H2O);
  uint*    H1   = (uint*)(ws + OFF_H1);
  ushortt* GX   = (ushortt*)(ws + OFF_GX);

  const int rec_lds = 36864*4 + 320*4;   // 148736 B
  (void)hipFuncSetAttribute(reinterpret_cast<const void*>(&rec_kernel<true>),
                            hipFuncAttributeMaxDynamicSharedMemorySize, rec_lds);
  (void)hipFuncSetAttribute(reinterpret_cast<const void*>(&rec_kernel<false>),
                            hipFuncAttributeMaxDynamicSharedMemorySize, rec_lds);

  prep_kernel<<<1248, 256, 0, stream>>>(W_ih0, W_hh0, W_ih1, W_hh1,
                                        PRF0, PLD0, PRF1, PLD1, PI0, PI1);
  gemm0_kernel<<<2048, 512, 0, stream>>>(x, PI0, b_ih0, b_hh0, GX);
  rec_kernel<true><<<BB, 1024, rec_lds, stream>>>((const uint4*)PRF0, (const uint4*)PLD0,
                                                  GX, b_hh0, H1, nullptr);
  gemm1_kernel<<<4096, 1024, 0, stream>>>(H1, PI1, b_ih1, b_hh1, GX);
  rec_kernel<false><<<BB, 1024, rec_lds, stream>>>((const uint4*)PRF1, (const uint4*)PLD1,
                                                   GX, b_hh1, nullptr, H2O);
  mlp_kernel<<<BB, 128, 0, stream>>>(H2O, W1, b1, W2, b2, (float*)d_out);
}

// Round 3
// 2076.986 us; speedup vs baseline: 1.0364x; 1.0039x over previous
//
#include <hip/hip_runtime.h>
#include <cstdint>
#include <cstddef>

typedef _Float16 h2_t __attribute__((ext_vector_type(2)));
typedef unsigned int uint;
typedef unsigned short ushortt;

#define BB 128
#define TT 512

// ---- ws layout (bytes) ----
#define OFF_PRF0 0u           // 15*1024*16 = 245760  (RF image, layer0)
#define OFF_PLD0 245760u      // 9*1024*16  = 147456  (LDS image)
#define OFF_PRF1 393216u      // 245760
#define OFF_PLD1 638976u      // 147456
#define OFF_PI0  786432u      // 98304
#define OFF_PI1  884736u      // 393216
#define OFF_H2O  1277952u     // 131072
#define OFF_H1   1409024u     // 33554432
#define OFF_GX   34963456u    // 100663296 (end ~135.6 MB)

__device__ __forceinline__ uint pack2(float a, float b){
  h2_t h; h.x = (_Float16)a; h.y = (_Float16)b;
  return __builtin_bit_cast(uint, h);
}
__device__ __forceinline__ float f16f(ushortt s){
  return (float)__builtin_bit_cast(_Float16, s);
}
__device__ __forceinline__ ushortt ff16(float f){
  return __builtin_bit_cast(ushortt, (_Float16)f);
}
__device__ __forceinline__ float dot2(uint w, uint h, float acc){
  return __builtin_amdgcn_fdot2(__builtin_bit_cast(h2_t, w),
                                __builtin_bit_cast(h2_t, h), acc, false);
}
__device__ __forceinline__ float d16(uint4 w, uint4 h, float a){
  a = dot2(w.x,h.x,a); a = dot2(w.y,h.y,a);
  a = dot2(w.z,h.z,a); a = dot2(w.w,h.w,a);
  return a;
}
template<int CTRL>
__device__ __forceinline__ float dpp_addf(float x){
  int p = __builtin_amdgcn_update_dpp(0, __float_as_int(x), CTRL, 0xF, 0xF, true);
  return x + __int_as_float(p);
}
template<int CTRL>
__device__ __forceinline__ float dpp_movf(float x){
  return __int_as_float(__builtin_amdgcn_update_dpp(0, __float_as_int(x), CTRL, 0xF, 0xF, true));
}
// sum over 4-lane quads, result in all 4 lanes (verified r4-r8)
__device__ __forceinline__ float red4(float x){
  x = dpp_addf<0xB1>(x); x = dpp_addf<0x4E>(x);
  return x;
}
// sum over 8-lane groups (q = lane&7), result in all 8 lanes (verified r1..r7)
__device__ __forceinline__ float red8(float x){
  x = dpp_addf<0xB1>(x); x = dpp_addf<0x4E>(x);
  int y = __builtin_amdgcn_ds_swizzle(__float_as_int(x), 0x101F);
  return x + __int_as_float(y);
}
__device__ __forceinline__ float sigf(float x){ return 1.0f/(1.0f+__expf(-x)); }
__device__ __forceinline__ float tanhf_(float x){
  x = fminf(15.0f, fmaxf(-15.0f, x));
  float e = __expf(2.0f*x);
  return (e-1.0f)/(e+1.0f);
}

// =================== prep: pack fp32 weights -> f16 images ===================
// REC org (r5/r7-verified): thread (q=tid&7, u=tid>>3, units 2u,2u+1);
// chunk c = r*4+k4, r = g*2+s: row = g*256+2u+s, dword e = cols 32q+8k4+2e,+1.
// r10/r11 split: c<15 -> PRF (register-resident), else -> PLD (LDS).
__global__ void prep_kernel(const float* __restrict__ W_ih0, const float* __restrict__ W_hh0,
                            const float* __restrict__ W_ih1, const float* __restrict__ W_hh1,
                            uint* __restrict__ PRF0, uint* __restrict__ PLD0,
                            uint* __restrict__ PRF1, uint* __restrict__ PLD1,
                            uint* __restrict__ PI0, uint* __restrict__ PI1)
{
  int i = blockIdx.x*256 + threadIdx.x;
  if (i < 196608) {
    const int layer = (i >= 98304) ? 1 : 0;
    const float* W = layer ? W_hh1 : W_hh0;
    int j = layer ? (i - 98304) : i;
    int e = j&3, r2 = j>>2;
    int tid = r2 & 1023, c = r2 >> 10;
    int q = tid&7, u = tid>>3, k4 = c&3, r = c>>2;
    int g = r>>1, s = r&1;
    int row = g*256 + 2*u + s, col = 32*q + 8*k4 + 2*e;
    uint val = pack2(W[row*256+col], W[row*256+col+1]);
    if (c < 15) (layer ? PRF1 : PRF0)[j]         = val;
    else        (layer ? PLD1 : PLD0)[j - 61440] = val;
  } else if (i < 221184) {
    int j2 = i - 196608;
    int jj = j2 & 255, rc = j2 >> 8;
    int ci = rc & 31, r = rc >> 5;
    PI0[j2] = pack2(W_ih0[(r*256+jj)*64 + 2*ci], W_ih0[(r*256+jj)*64 + 2*ci + 1]);
  } else if (i < 319488) {
    int j3 = i - 221184;
    int tid = j3 & 1023, rc = j3 >> 10;
    int ci = rc & 31, r = rc >> 5;
    int kq = tid & 3, jj = tid >> 2;
    int col = 64*kq + 2*ci;
    PI1[j3] = pack2(W_ih1[(r*256+jj)*256 + col], W_ih1[(r*256+jj)*256 + col + 1]);
  }
}

// =================== GEMM0: gx0 = W_ih0 . x + biases (unchanged from r5) ===================
__global__ __launch_bounds__(512) void gemm0_kernel(
    const float* __restrict__ x, const uint* __restrict__ PI0,
    const float* __restrict__ b_ih0, const float* __restrict__ b_hh0,
    ushortt* __restrict__ gx)
{
  const int blk = blockIdx.x;
  const int b = blk >> 4, t0 = (blk & 15) * 32;
  const int tid = threadIdx.x;
  const int j = tid & 255, th = tid >> 8;
  __shared__ uint xs[32*32];
  {
    float4 v = ((const float4*)x)[((size_t)b*TT + t0 + (tid>>4))*16 + (tid&15)];
    xs[(tid>>4)*32 + (tid&15)*2]     = pack2(v.x, v.y);
    xs[(tid>>4)*32 + (tid&15)*2 + 1] = pack2(v.z, v.w);
  }
  uint w[96];
  #pragma unroll
  for (int rc = 0; rc < 96; ++rc) w[rc] = PI0[rc*256 + j];
  const float br = b_ih0[j] + b_hh0[j];
  const float bz = b_ih0[256+j] + b_hh0[256+j];
  const float bn = b_ih0[512+j];
  __syncthreads();
  ushortt* gout = gx + ((size_t)b*TT + t0 + th*16)*768;
  #pragma unroll 1
  for (int tt = 0; tt < 16; ++tt) {
    const uint* xr = xs + (th*16 + tt)*32;
    float ar=0.f, az=0.f, an=0.f;
    #pragma unroll
    for (int c = 0; c < 32; ++c) {
      uint xv = xr[c];
      ar = dot2(w[c],    xv, ar);
      az = dot2(w[32+c], xv, az);
      an = dot2(w[64+c], xv, an);
    }
    gout[j]     = ff16(ar + br);
    gout[256+j] = ff16(az + bz);
    gout[512+j] = ff16(an + bn);
    gout += 768;
  }
}

// =================== GEMM1: gx1 = W_ih1 . h1 + biases (r12: honest occupancy bound) ===================
__global__ __launch_bounds__(1024, 4) void gemm1_kernel(
    const uint* __restrict__ h1, const uint* __restrict__ PI1,
    const float* __restrict__ b_ih1, const float* __restrict__ b_hh1,
    ushortt* __restrict__ gx)
{
  const int blk = blockIdx.x;
  const int b = blk >> 5, t0 = (blk & 31) * 16;
  const int tid = threadIdx.x;
  const int kq = tid & 3, j = tid >> 2;
  __shared__ uint hsT[16*144];
  {
    uint2 v = ((const uint2*)(h1 + ((size_t)b*TT + t0)*128))[tid];
    int f = 2*tid, tp = f>>7, c = f&127, s = c>>2, e = c&3;
    *(uint2*)&hsT[tp*144 + (s + (s>>3))*4 + e] = v;
  }
  uint w[96];
  #pragma unroll
  for (int rc = 0; rc < 96; ++rc) w[rc] = PI1[rc*1024 + tid];
  const float br = b_ih1[j] + b_hh1[j];
  const float bz = b_ih1[256+j] + b_hh1[256+j];
  const float bn = b_ih1[512+j];
  __syncthreads();
  ushortt* gout = gx + ((size_t)b*TT + t0)*768;
  #pragma unroll 1
  for (int tt = 0; tt < 16; ++tt) {
    const uint4* hr = (const uint4*)&hsT[tt*144];
    float ar=0.f, az=0.f, an=0.f;
    #pragma unroll
    for (int i = 0; i < 8; ++i) {
      uint4 hv = hr[9*kq + i];
      ar = dot2(w[4*i],hv.x,ar);    ar = dot2(w[4*i+1],hv.y,ar);
      ar = dot2(w[4*i+2],hv.z,ar);  ar = dot2(w[4*i+3],hv.w,ar);
      az = dot2(w[32+4*i],hv.x,az); az = dot2(w[32+4*i+1],hv.y,az);
      az = dot2(w[32+4*i+2],hv.z,az); az = dot2(w[32+4*i+3],hv.w,az);
      an = dot2(w[64+4*i],hv.x,an); an = dot2(w[64+4*i+1],hv.y,an);
      an = dot2(w[64+4*i+2],hv.z,an); an = dot2(w[64+4*i+3],hv.w,an);
    }
    ar = red4(ar); az = red4(az); an = red4(an);
    if (kq == 0) {
      gout[j]     = ff16(ar + br);
      gout[256+j] = ff16(az + bz);
      gout[512+j] = ff16(an + bn);
    }
    gout += 768;
  }
}

// =================== REC: serial GRU recurrence (r12: honest occupancy bound) ===================
// r10/r11 post-mortem: VGPR_Count stayed 60 because the default launch_bounds
// heuristic capped allocation at 64 VGPRs (8 waves/EU target) -- it cannot see
// the 148 KB dynamic LDS that limits us to 1 block/CU (4 waves/EU) regardless.
// Under that cap the allocator MUST rematerialize the 15 PRF quad-loads each
// step: 245 KB/CU/step through L1 ~= the whole 4150 cy/step.
// r12: __launch_bounds__(1024, 4) -> VGPR cap 128. Live set with k4-outer/JIT-hk
// ~= 60 w + 4 hk + 6 acc + ~25 misc < 128, so the in-loop pin is now satisfiable
// with true register residency. Numerics unchanged.
template<bool IS_L0>
__global__ __launch_bounds__(1024, 4) void rec_kernel(
    const uint4* __restrict__ PRF, const uint4* __restrict__ PLD,
    const ushortt* __restrict__ GX, const float* __restrict__ b_hh,
    uint* __restrict__ h1, float* __restrict__ h2o)
{
  extern __shared__ uint lds_u[];           // [0,36864): ldsw quads; [36864,37184): h dbuf
  uint4* ldsw  = (uint4*)lds_u;             // [1024][9] per-thread-private (c=15..23)
  uint*  hbase = lds_u + 36864;             // 2 x 160 uints (padded phys = c + 4*(c>>4))
  const int b = blockIdx.x, tid = threadIdx.x;
  const int q = tid & 7, u = tid >> 3;

  #pragma unroll
  for (int i = 0; i < 9; ++i) ldsw[tid*9 + i] = PLD[i*1024 + tid];
  if (tid < 320) hbase[tid] = 0;

  uint w[60];
  #pragma unroll
  for (int c = 0; c < 15; ++c) {
    uint4 v = PRF[c*1024 + tid];
    w[4*c] = v.x; w[4*c+1] = v.y; w[4*c+2] = v.z; w[4*c+3] = v.w;
  }

  const int j = 2*u + q;                // unit index (valid for q<2)
  const bool gl = (q < 2);
  const ushortt* gxp = GX + (size_t)b*TT*768;
  const float bhn = gl ? b_hh[512 + j] : 0.f;
  ushortt gr0=0, gz0=0, gn0=0, gr1=0, gz1=0, gn1=0;
  if (gl) {
    gr0 = gxp[j]; gz0 = gxp[256+j]; gn0 = gxp[512+j];
    gr1 = gxp[768+j]; gz1 = gxp[768+256+j]; gn1 = gxp[768+512+j];
  }
  float h_old = 0.f;
  __syncthreads();
  int cur = 0;
  #pragma unroll 1
  for (int t = 0; t < TT; ++t) {
    // In-loop pin: each iteration's asm is opaque -> the 60 weight words are
    // loop-carried VGPRs that cannot be rematerialized from PRF.
    #pragma unroll
    for (int c = 0; c < 60; ++c) asm volatile("" : "+v"(w[c]));

    const uint4* hr = (const uint4*)&hbase[cur*160];
    float a[6] = {0.f,0.f,0.f,0.f,0.f,0.f};   // a[r], r=g*2+s: r/z/n gates x units 2u,2u+1
    // k4-outer, gate-inner: only one hk quad live at a time.
    #pragma unroll
    for (int k4 = 0; k4 < 4; ++k4) {
      uint4 hk = hr[5*q + k4];               // phys 20q+4k4, conflict-free (r7)
      #pragma unroll
      for (int r6 = 0; r6 < 6; ++r6) {
        const int c = r6*4 + k4;
        if (c < 15) {
          uint4 wv; wv.x = w[4*c]; wv.y = w[4*c+1]; wv.z = w[4*c+2]; wv.w = w[4*c+3];
          a[r6] = d16(wv, hk, a[r6]);
        } else {
          a[r6] = d16(ldsw[tid*9 + (c - 15)], hk, a[r6]);
        }
      }
    }
    #pragma unroll
    for (int r6 = 0; r6 < 6; ++r6) a[r6] = red8(a[r6]);

    const bool odd = (q & 1);
    float Sr = odd ? a[1] : a[0];
    float Sz = odd ? a[3] : a[2];
    float Sn = odd ? a[5] : a[4];
    float r = sigf(f16f(gr0) + Sr);
    float z = sigf(f16f(gz0) + Sz);
    float n = tanhf_(f16f(gn0) + r*(Sn + bhn));
    float hn = z*(h_old - n) + n;
    if (gl) h_old = hn;
    gr0 = gr1; gz0 = gz1; gn0 = gn1;
    if (gl && t + 2 < TT) {
      const ushortt* p = gxp + (size_t)(t+2)*768;
      gr1 = p[j]; gz1 = p[256+j]; gn1 = p[512+j];
    }
    float hx = dpp_movf<0xB1>(hn);
    uint hv2 = pack2(hn, hx);
    if (q == 0) {
      hbase[(cur^1)*160 + u + 4*(u>>4)] = hv2;
      if (IS_L0) h1[((size_t)b*TT + t)*128 + u] = hv2;
    }
    if (!IS_L0 && t == TT-1 && gl) h2o[b*256 + j] = hn;
    // LDS-only barrier: drain ds ops, leave global prefetch (vmcnt) in flight.
    asm volatile("s_waitcnt lgkmcnt(0)\n\ts_barrier" ::: "memory");
    cur ^= 1;
  }
}

// =================== MLP head (unchanged) ===================
__global__ __launch_bounds__(128) void mlp_kernel(
    const float* __restrict__ h2, const float* __restrict__ W1,
    const float* __restrict__ b1, const float* __restrict__ W2,
    const float* __restrict__ b2, float* __restrict__ out)
{
  __shared__ float hls[256];
  __shared__ float red[128];
  const int b = blockIdx.x, tid = threadIdx.x;
  if (tid < 64) ((float4*)hls)[tid] = ((const float4*)(h2 + (size_t)b*256))[tid];
  __syncthreads();
  float acc = b1[tid];
  const float4* w4 = (const float4*)(W1 + (size_t)tid*256);
  const float4* h4 = (const float4*)hls;
  #pragma unroll 8
  for (int k = 0; k < 64; ++k) {
    float4 w = w4[k]; float4 h = h4[k];
    acc = fmaf(w.x,h.x,acc); acc = fmaf(w.y,h.y,acc);
    acc = fmaf(w.z,h.z,acc); acc = fmaf(w.w,h.w,acc);
  }
  red[tid] = fmaxf(acc, 0.0f) * W2[tid];
  __syncthreads();
  for (int s = 64; s > 0; s >>= 1) {
    if (tid < s) red[tid] += red[tid + s];
    __syncthreads();
  }
  if (tid == 0) out[b] = red[0] + b2[0];
}

extern "C" void kernel_launch(void* const* d_in, const int* in_sizes, int n_in,
                              void* d_out, int out_size, void* d_ws, size_t ws_size,
                              hipStream_t stream)
{
  const float* x     = (const float*)d_in[0];
  const float* W_ih0 = (const float*)d_in[1];
  const float* W_hh0 = (const float*)d_in[2];
  const float* b_ih0 = (const float*)d_in[3];
  const float* b_hh0 = (const float*)d_in[4];
  const float* W_ih1 = (const float*)d_in[5];
  const float* W_hh1 = (const float*)d_in[6];
  const float* b_ih1 = (const float*)d_in[7];
  const float* b_hh1 = (const float*)d_in[8];
  const float* W1    = (const float*)d_in[9];
  const float* b1    = (const float*)d_in[10];
  const float* W2    = (const float*)d_in[11];
  const float* b2    = (const float*)d_in[12];

  char* ws = (char*)d_ws;
  uint*    PRF0 = (uint*)(ws + OFF_PRF0);
  uint*    PLD0 = (uint*)(ws + OFF_PLD0);
  uint*    PRF1 = (uint*)(ws + OFF_PRF1);
  uint*    PLD1 = (uint*)(ws + OFF_PLD1);
  uint*    PI0  = (uint*)(ws + OFF_PI0);
  uint*    PI1  = (uint*)(ws + OFF_PI1);
  float*   H2O  = (float*)(ws + OFF_H2O);
  uint*    H1   = (uint*)(ws + OFF_H1);
  ushortt* GX   = (ushortt*)(ws + OFF_GX);

  const int rec_lds = 36864*4 + 320*4;   // 148736 B
  (void)hipFuncSetAttribute(reinterpret_cast<const void*>(&rec_kernel<true>),
                            hipFuncAttributeMaxDynamicSharedMemorySize, rec_lds);
  (void)hipFuncSetAttribute(reinterpret_cast<const void*>(&rec_kernel<false>),
                            hipFuncAttributeMaxDynamicSharedMemorySize, rec_lds);

  prep_kernel<<<1248, 256, 0, stream>>>(W_ih0, W_hh0, W_ih1, W_hh1,
                                        PRF0, PLD0, PRF1, PLD1, PI0, PI1);
  gemm0_kernel<<<2048, 512, 0, stream>>>(x, PI0, b_ih0, b_hh0, GX);
  rec_kernel<true><<<BB, 1024, rec_lds, stream>>>((const uint4*)PRF0, (const uint4*)PLD0,
                                                  GX, b_hh0, H1, nullptr);
  gemm1_kernel<<<4096, 1024, 0, stream>>>(H1, PI1, b_ih1, b_hh1, GX);
  rec_kernel<false><<<BB, 1024, rec_lds, stream>>>((const uint4*)PRF1, (const uint4*)PLD1,
                                                   GX, b_hh1, nullptr, H2O);
  mlp_kernel<<<BB, 128, 0, stream>>>(H2O, W1, b1, W2, b2, (float*)d_out);
}